// Round 5
// baseline (492.725 us; speedup 1.0000x reference)
//
#include <hip/hip_runtime.h>

#define HIDDEN 512
#define BLK_ELEMS (64 * 128 * 8)   // elements per (128-row x 512-col) tiled block

typedef __attribute__((ext_vector_type(8))) short short8;
typedef __attribute__((ext_vector_type(4))) float f32x4;

__device__ __forceinline__ unsigned short f2bf(float f) {
    unsigned u = __float_as_uint(f);
    unsigned r = (u + 0x7FFFu + ((u >> 16) & 1u)) >> 16;
    return (unsigned short)r;
}
__device__ __forceinline__ float bf2f(unsigned short h) {
    return __uint_as_float(((unsigned)h) << 16);
}

__device__ __forceinline__ void load_lds16(const unsigned short* g, unsigned short* l) {
    __builtin_amdgcn_global_load_lds(
        (const __attribute__((address_space(1))) unsigned int*)(g),
        (__attribute__((address_space(3))) unsigned int*)(l), 16, 0, 0);
}

__device__ __forceinline__ void acc8(uint4 v, float cf, float* a) {
    a[0] = fmaf(cf, bf2f((unsigned short)(v.x & 0xFFFF)), a[0]);
    a[1] = fmaf(cf, bf2f((unsigned short)(v.x >> 16)),    a[1]);
    a[2] = fmaf(cf, bf2f((unsigned short)(v.y & 0xFFFF)), a[2]);
    a[3] = fmaf(cf, bf2f((unsigned short)(v.y >> 16)),    a[3]);
    a[4] = fmaf(cf, bf2f((unsigned short)(v.z & 0xFFFF)), a[4]);
    a[5] = fmaf(cf, bf2f((unsigned short)(v.z >> 16)),    a[5]);
    a[6] = fmaf(cf, bf2f((unsigned short)(v.w & 0xFFFF)), a[6]);
    a[7] = fmaf(cf, bf2f((unsigned short)(v.w >> 16)),    a[7]);
}

// ---------------- cast fp32 row-major -> tiled bf16 (per-chunk form; weights) ----------------
// tiled layout: [row/128][kchunk(64)][row%128][8 bf16]

__device__ __forceinline__ void cast_chunk(const float* __restrict__ src,
                                           unsigned short* __restrict__ dst,
                                           int rows, int o) {
    int blk = o >> 13;
    int rem = o & 8191;
    int g = rem >> 7;
    int m = rem & 127;
    int row = blk * 128 + m;
    short8 v;
    if (row < rows) {
        const float* p = src + (size_t)row * HIDDEN + g * 8;
        float4 f0 = *(const float4*)p;
        float4 f1 = *(const float4*)(p + 4);
        v[0] = (short)f2bf(f0.x); v[1] = (short)f2bf(f0.y);
        v[2] = (short)f2bf(f0.z); v[3] = (short)f2bf(f0.w);
        v[4] = (short)f2bf(f1.x); v[5] = (short)f2bf(f1.y);
        v[6] = (short)f2bf(f1.z); v[7] = (short)f2bf(f1.w);
    } else {
        v = (short8)0;
    }
    *(short8*)(dst + (size_t)o * 8) = v;
}

// ---------------- fused: edge-count | cast x (block-transpose, coalesced) ----------------

__global__ __launch_bounds__(256)
void fused_count_castx(const int* __restrict__ dstv, int* __restrict__ cnt, int E, int countB,
                       const float* __restrict__ x, unsigned short* __restrict__ bufA,
                       int rows, int nxb) {
    int b = blockIdx.x;
    if (b < countB) {
        int e = b * 256 + threadIdx.x;
        if (e < E) atomicAdd(&cnt[dstv[e]], 1);
        return;
    }
    int cb = b - countB;
    if (cb >= nxb) return;
    __shared__ __align__(16) unsigned short xs[32 * 520];   // 520 = 512 + 8 pad
    const int tid = threadIdx.x;
    const int r0 = cb * 32;
    #pragma unroll
    for (int p = 0; p < 16; ++p) {
        int f = p * 1024 + tid * 4;          // flat float index in [32][512]
        int rl = f >> 9;
        int col = f & 511;
        int grow = r0 + rl;
        uint2 w = make_uint2(0u, 0u);
        if (grow < rows) {
            float4 v = *(const float4*)(x + (size_t)grow * HIDDEN + col);
            w.x = (unsigned)f2bf(v.x) | ((unsigned)f2bf(v.y) << 16);
            w.y = (unsigned)f2bf(v.z) | ((unsigned)f2bf(v.w) << 16);
        }
        *(uint2*)(xs + rl * 520 + col) = w;
    }
    __syncthreads();
    const int blk = r0 >> 7;
    const int m0 = r0 & 127;
    unsigned short* dstb = bufA + (size_t)blk * BLK_ELEMS;
    #pragma unroll
    for (int p = 0; p < 8; ++p) {
        int c = p * 256 + tid;
        int g = c >> 5;
        int mloc = c & 31;
        short8 v = *(const short8*)(xs + mloc * 520 + g * 8);
        *(short8*)(dstb + g * 1024 + (m0 + mloc) * 8) = v;
    }
}

// ---------------- fused: per-block sums + norm | cast W1/W2/Wc ----------------

__global__ __launch_bounds__(256)
void fused_bsum_castw(const int* __restrict__ cnt, float* __restrict__ norm,
                      int* __restrict__ bsums, int n, int NSB,
                      const float* __restrict__ W1, const float* __restrict__ W2,
                      const float* __restrict__ Wc,
                      unsigned short* __restrict__ W1t, unsigned short* __restrict__ W2t,
                      unsigned short* __restrict__ Wct, int NC) {
    __shared__ int red[256];
    int tid = threadIdx.x;
    if ((int)blockIdx.x < NSB) {
        int i = blockIdx.x * 256 + tid;
        int v = 0;
        if (i < n) {
            v = cnt[i];
            norm[i] = rsqrtf((float)(v + 1));
        }
        red[tid] = v;
        __syncthreads();
        #pragma unroll
        for (int off = 128; off > 0; off >>= 1) {
            if (tid < off) red[tid] += red[tid + off];
            __syncthreads();
        }
        if (tid == 0) bsums[blockIdx.x] = red[0];
    } else {
        int o = ((int)blockIdx.x - NSB) * 256 + tid;
        if (o < 32768) {
            cast_chunk(W1, W1t, HIDDEN, o);
        } else if (o < 65536) {
            cast_chunk(W2, W2t, HIDDEN, o - 32768);
        } else if (o < 73728) {
            cast_chunk(Wc, Wct, NC, o - 65536);
        }
    }
}

// scans nb (<=256) block sums; writes exclusive offsets + total into rowptr[n]
__global__ __launch_bounds__(256)
void bscan_kernel(const int* __restrict__ bsums, int* __restrict__ boffs,
                  int* __restrict__ rowptr_n, int nb) {
    __shared__ int buf[256];
    int tid = threadIdx.x;
    int v = (tid < nb) ? bsums[tid] : 0;
    buf[tid] = v;
    __syncthreads();
    #pragma unroll
    for (int off = 1; off < 256; off <<= 1) {
        int t = (tid >= off) ? buf[tid - off] : 0;
        __syncthreads();
        buf[tid] += t;
        __syncthreads();
    }
    if (tid < nb) boffs[tid] = buf[tid] - v;
    if (tid == 255) rowptr_n[0] = buf[255];
}

__global__ __launch_bounds__(256)
void scan_final_kernel(const int* __restrict__ cnt, const int* __restrict__ boffs,
                       int* __restrict__ rowptr, int* __restrict__ cursor, int n) {
    __shared__ int buf[256];
    int tid = threadIdx.x;
    int i = blockIdx.x * 256 + tid;
    int v = (i < n) ? cnt[i] : 0;
    buf[tid] = v;
    __syncthreads();
    #pragma unroll
    for (int off = 1; off < 256; off <<= 1) {
        int t = (tid >= off) ? buf[tid - off] : 0;
        __syncthreads();
        buf[tid] += t;
        __syncthreads();
    }
    if (i < n) {
        int ex = boffs[blockIdx.x] + buf[tid] - v;
        rowptr[i] = ex;
        cursor[i] = ex;
    }
}

// ---------------- bf16 MFMA GEMM body (128x128 tile; gemm1-in-fused + classifier) ----

template<int MODE>
__device__ __forceinline__ void gemm_body(const unsigned short* __restrict__ At,
                                          const unsigned short* __restrict__ Bt,
                                          const float* __restrict__ bias,
                                          void* __restrict__ Cout,
                                          int M, int NC, int mb, int nb) {
    __shared__ __align__(16) unsigned short As[8 * 128 * 8];  // 16 KB: [g][m][8]
    __shared__ __align__(16) unsigned short Bs[8 * 128 * 8];

    const int tid = threadIdx.x;
    const int wid = tid >> 6;
    const int lane = tid & 63;
    const int wm = wid & 1, wn = wid >> 1;
    const int lm = lane & 15;
    const int lq = lane >> 4;

    const unsigned short* Ab = At + (size_t)mb * BLK_ELEMS;
    const unsigned short* Bb = Bt + (size_t)nb * BLK_ELEMS;

    f32x4 acc[4][4];
    #pragma unroll
    for (int i = 0; i < 4; ++i)
        #pragma unroll
        for (int j = 0; j < 4; ++j) acc[i][j] = (f32x4)0.f;

    for (int kt = 0; kt < 8; ++kt) {
        __syncthreads();
        const unsigned short* ga = Ab + kt * (8 * 1024);
        const unsigned short* gb = Bb + kt * (8 * 1024);
        #pragma unroll
        for (int i = 0; i < 4; ++i) {
            int off = (tid + i * 256) * 8;
            load_lds16(ga + off, As + off);
            load_lds16(gb + off, Bs + off);
        }
        __syncthreads();
        #pragma unroll
        for (int ks = 0; ks < 2; ++ks) {
            int g = ks * 4 + lq;
            int base = g * 1024 + lm * 8;
            short8 af[4], bfr[4];
            #pragma unroll
            for (int mt = 0; mt < 4; ++mt)
                af[mt] = *(const short8*)&As[base + (wm * 64 + mt * 16) * 8];
            #pragma unroll
            for (int nt = 0; nt < 4; ++nt)
                bfr[nt] = *(const short8*)&Bs[base + (wn * 64 + nt * 16) * 8];
            #pragma unroll
            for (int mt = 0; mt < 4; ++mt)
                #pragma unroll
                for (int nt = 0; nt < 4; ++nt)
                    acc[mt][nt] = __builtin_amdgcn_mfma_f32_16x16x32_bf16(
                        af[mt], bfr[nt], acc[mt][nt], 0, 0, 0);
        }
    }

    #pragma unroll
    for (int mt = 0; mt < 4; ++mt) {
        #pragma unroll
        for (int nt = 0; nt < 4; ++nt) {
            int col = nb * 128 + wn * 64 + nt * 16 + lm;
            f32x4 v = acc[mt][nt];
            #pragma unroll
            for (int r = 0; r < 4; ++r) {
                int row = mb * 128 + wm * 64 + mt * 16 + lq * 4 + r;
                if (row < M) {
                    if (MODE == 0) {
                        ((unsigned short*)Cout)[(size_t)row * HIDDEN + col] = f2bf(v[r]);
                    } else {
                        if (col < NC)
                            ((float*)Cout)[(size_t)row * NC + col] = v[r] + bias[col];
                    }
                }
            }
        }
    }
}

// XCD-grouped swizzle: 4 nb blocks of one mb land on one XCD back-to-back
__device__ __forceinline__ bool swz_decode(int bid, int NB, int& mb, int& nb) {
    int p = bid & 7;
    int s = bid >> 3;
    nb = s & 3;
    mb = (s >> 2) * 8 + p;
    return mb < NB;
}

template<int MODE>
__global__ __launch_bounds__(256)
void gemm_plain(const unsigned short* __restrict__ At, const unsigned short* __restrict__ Bt,
                const float* __restrict__ bias, void* __restrict__ Cout,
                int M, int NC) {
    gemm_body<MODE>(At, Bt, bias, Cout, M, NC, blockIdx.x, blockIdx.y);
}

// ---------------- fused: CSR fill | gemm layer-1 ----------------

__global__ __launch_bounds__(256)
void fused_fill_gemm1(const int* __restrict__ src, const int* __restrict__ dstv,
                      const float* __restrict__ norm, int* __restrict__ cursor,
                      int2* __restrict__ epair, int E, int fillB,
                      const unsigned short* __restrict__ At, const unsigned short* __restrict__ Bt,
                      void* __restrict__ Cout, int M, int NB) {
    int b = blockIdx.x;
    if (b < fillB) {
        int e = b * 256 + threadIdx.x;
        if (e < E) {
            int s = src[e], d = dstv[e];
            float cf = norm[s] * norm[d];
            int p = atomicAdd(&cursor[d], 1);
            epair[p] = make_int2(s, __float_as_int(cf));
        }
    } else {
        int mb, nb;
        if (swz_decode(b - fillB, NB, mb, nb))
            gemm_body<0>(At, Bt, nullptr, Cout, M, HIDDEN, mb, nb);
    }
}

// ---------------- gemm256: 256x256 tile, BK=64, double-buffered LDS, counted vmcnt ----
// R5: T3+T4 port (guide §5.5) adapted to our tiled layout. Each K-tile (8 g-chunks)
// of a 128-row slab is a CONTIGUOUS 16KB in global -> global_load_lds stays linear,
// LDS layout [slab][g][m][8] keeps the proven conflict-free ds_read pattern, no
// swizzle needed. Next K-tile's 8 loads are issued BEFORE compute; s_waitcnt
// vmcnt(8) (never 0 mid-loop) + raw s_barrier (asm, "memory") instead of
// __syncthreads' full drain. setprio(1) around the MFMA cluster (T5).
// 512 thr = 8 waves (2M x 4N), wave-tile 128x64, acc 8x4 frags (128 VGPR).
// LDS 128KB -> 1 block/CU, 2 waves/SIMD (template occupancy).

__device__ __forceinline__ void stage256(const unsigned short* __restrict__ At, size_t aBase,
                                         const unsigned short* __restrict__ Bt, size_t bBase,
                                         int kt, unsigned short* dst, int tid) {
    #pragma unroll
    for (int i = 0; i < 4; ++i) {
        int f = i * 4096 + tid * 8;          // elem offset in 16K-elem (32KB) region
        int sl = f >> 13;                    // slab 0/1
        int rem = f & 8191;
        load_lds16(At + aBase + (size_t)sl * BLK_ELEMS + (size_t)kt * 8192 + rem, dst + f);
        load_lds16(Bt + bBase + (size_t)sl * BLK_ELEMS + (size_t)kt * 8192 + rem, dst + 16384 + f);
    }
}

__global__ __launch_bounds__(512)
void gemm256_swz(const unsigned short* __restrict__ At, const unsigned short* __restrict__ Bt,
                 unsigned short* __restrict__ Cout, int M, int MB2) {
    // XCD-grouped decode; nbt = 2 (N=512 / 256)
    int p = blockIdx.x & 7;
    int s = blockIdx.x >> 3;
    int nb = s & 1;
    int mb = (s >> 1) * 8 + p;
    if (mb >= MB2) return;

    __shared__ __align__(16) unsigned short lds[2 * 32768];   // 128 KB

    const int tid = threadIdx.x;
    const int wid = tid >> 6;
    const int lane = tid & 63;
    const int wm = wid & 1;        // M half (128 rows)
    const int wn = wid >> 1;       // N quarter (64 cols)
    const int lm = lane & 15;
    const int lq = lane >> 4;

    const size_t aBase = (size_t)(2 * mb) * BLK_ELEMS;
    const size_t bBase = (size_t)(2 * nb) * BLK_ELEMS;

    f32x4 acc[8][4];
    #pragma unroll
    for (int i = 0; i < 8; ++i)
        #pragma unroll
        for (int j = 0; j < 4; ++j) acc[i][j] = (f32x4)0.f;

    stage256(At, aBase, Bt, bBase, 0, lds, tid);

    for (int kt = 0; kt < 8; ++kt) {
        const int cur = kt & 1;
        if (kt < 7) {
            stage256(At, aBase, Bt, bBase, kt + 1, lds + (cur ^ 1) * 32768, tid);
            asm volatile("s_waitcnt vmcnt(8)" ::: "memory");   // cur's 8 done; next 8 in flight
        } else {
            asm volatile("s_waitcnt vmcnt(0)" ::: "memory");
        }
        asm volatile("s_barrier" ::: "memory");                // all waves' cur writes landed

        const unsigned short* As = lds + cur * 32768;
        const unsigned short* Bs = As + 16384;
        __builtin_amdgcn_s_setprio(1);
        #pragma unroll
        for (int ks = 0; ks < 2; ++ks) {
            const int g = ks * 4 + lq;
            short8 bfr[4];
            #pragma unroll
            for (int nt = 0; nt < 4; ++nt) {
                int cc = (wn & 1) * 64 + nt * 16 + lm;
                bfr[nt] = *(const short8*)&Bs[(wn >> 1) * 8192 + g * 1024 + cc * 8];
            }
            #pragma unroll
            for (int mt = 0; mt < 8; ++mt) {
                short8 af = *(const short8*)&As[wm * 8192 + g * 1024 + (mt * 16 + lm) * 8];
                #pragma unroll
                for (int nt = 0; nt < 4; ++nt)
                    acc[mt][nt] = __builtin_amdgcn_mfma_f32_16x16x32_bf16(
                        af, bfr[nt], acc[mt][nt], 0, 0, 0);
            }
        }
        __builtin_amdgcn_s_setprio(0);
        asm volatile("s_barrier" ::: "memory");                // done reading cur before restage
    }

    #pragma unroll
    for (int mt = 0; mt < 8; ++mt) {
        #pragma unroll
        for (int nt = 0; nt < 4; ++nt) {
            int col = nb * 256 + wn * 64 + nt * 16 + lm;
            f32x4 v = acc[mt][nt];
            #pragma unroll
            for (int r = 0; r < 4; ++r) {
                int row = mb * 256 + wm * 128 + mt * 16 + lq * 4 + r;
                if (row < M)
                    Cout[(size_t)row * HIDDEN + col] = f2bf(v[r]);
            }
        }
    }
}

// ---------------- aggregation: wave-per-node, 16 waves/block (R0 proven form) ----
// BW pinned at 3.7-4.1 TB/s across 3 concurrency configs (R0-R2) -> structural
// floor for the random-1KB-gather mix. Do NOT add launch_bounds min-waves
// ((1024,8) spilled accumulators to scratch, R2: WRITE 454MB, 2.6x slower).

__global__ __launch_bounds__(1024)
void aggregate_kernel(const unsigned short* __restrict__ h, const int* __restrict__ rowptr,
                      const int2* __restrict__ epair, const float* __restrict__ norm,
                      const float* __restrict__ bias, unsigned short* __restrict__ out_t,
                      int N) {
    const int wave = threadIdx.x >> 6;
    const int lane = threadIdx.x & 63;
    const int node = blockIdx.x * 16 + wave;
    if (node >= N) return;
    const uint4* h4 = (const uint4*)h;   // 64 chunks of 16B per row
    const int c = lane;

    float a[8];
    {
        uint4 sv = h4[(size_t)node * 64 + c];
        float nv = norm[node];
        float invd = nv * nv;
        a[0] = a[1] = a[2] = a[3] = a[4] = a[5] = a[6] = a[7] = 0.f;
        acc8(sv, invd, a);
    }

    int beg = rowptr[node], end = rowptr[node + 1];
    int j = beg;
    for (; j + 4 <= end; j += 4) {
        int2 p0 = epair[j + 0];
        int2 p1 = epair[j + 1];
        int2 p2 = epair[j + 2];
        int2 p3 = epair[j + 3];
        uint4 v0 = h4[(size_t)p0.x * 64 + c];
        uint4 v1 = h4[(size_t)p1.x * 64 + c];
        uint4 v2 = h4[(size_t)p2.x * 64 + c];
        uint4 v3 = h4[(size_t)p3.x * 64 + c];
        acc8(v0, __int_as_float(p0.y), a);
        acc8(v1, __int_as_float(p1.y), a);
        acc8(v2, __int_as_float(p2.y), a);
        acc8(v3, __int_as_float(p3.y), a);
    }
    for (; j < end; ++j) {
        int2 p = epair[j];
        uint4 v = h4[(size_t)p.x * 64 + c];
        acc8(v, __int_as_float(p.y), a);
    }

    const float4 b0 = *(const float4*)(bias + c * 8);
    const float4 b1 = *(const float4*)(bias + c * 8 + 4);
    a[0] = fmaxf(a[0] + b0.x, 0.f); a[1] = fmaxf(a[1] + b0.y, 0.f);
    a[2] = fmaxf(a[2] + b0.z, 0.f); a[3] = fmaxf(a[3] + b0.w, 0.f);
    a[4] = fmaxf(a[4] + b1.x, 0.f); a[5] = fmaxf(a[5] + b1.y, 0.f);
    a[6] = fmaxf(a[6] + b1.z, 0.f); a[7] = fmaxf(a[7] + b1.w, 0.f);

    size_t off = (size_t)(node >> 7) * BLK_ELEMS + (size_t)c * 1024 + (node & 127) * 8;
    uint4 o;
    o.x = (unsigned)f2bf(a[0]) | ((unsigned)f2bf(a[1]) << 16);
    o.y = (unsigned)f2bf(a[2]) | ((unsigned)f2bf(a[3]) << 16);
    o.z = (unsigned)f2bf(a[4]) | ((unsigned)f2bf(a[5]) << 16);
    o.w = (unsigned)f2bf(a[6]) | ((unsigned)f2bf(a[7]) << 16);
    *(uint4*)(out_t + off) = o;
}

// ---------------- launch ----------------

extern "C" void kernel_launch(void* const* d_in, const int* in_sizes, int n_in,
                              void* d_out, int out_size, void* d_ws, size_t ws_size,
                              hipStream_t stream) {
    const float* x  = (const float*)d_in[0];
    const int*   ei = (const int*)d_in[1];
    const float* W1 = (const float*)d_in[2];
    const float* b1 = (const float*)d_in[3];
    const float* W2 = (const float*)d_in[4];
    const float* b2 = (const float*)d_in[5];
    const float* Wc = (const float*)d_in[6];
    const float* bc = (const float*)d_in[7];

    const int N  = in_sizes[0] / HIDDEN;      // 50000
    const int E  = in_sizes[1] / 2;           // 500000
    const int NC = in_sizes[6] / HIDDEN;      // 100
    const int NB = (N + 127) / 128;           // 391
    const int NSB = (N + 255) / 256;          // 196
    const int MB2 = (N + 255) / 256;          // 196 (256-row tiles)

    const int* src = ei;
    const int* dst = ei + E;

    char* ws = (char*)d_ws;
    int*   cnt    = (int*)(ws);
    int*   rowptr = (int*)(ws + (256 << 10));
    int*   cursor = (int*)(ws + (512 << 10));
    float* normv  = (float*)(ws + (768 << 10));
    int*   bsums  = (int*)(ws + (968 << 10));
    int*   boffs  = (int*)(ws + (990 << 10));
    int2*  epair  = (int2*)(ws + (1ull << 20));                 // E*8 B = 4 MB
    unsigned short* W1t = (unsigned short*)(ws + (6ull << 20));
    unsigned short* W2t = (unsigned short*)(ws + (6ull << 20) + (512 << 10));
    unsigned short* Wct = (unsigned short*)(ws + (7ull << 20));
    unsigned short* bufA = (unsigned short*)(ws + (16ull << 20));
    unsigned short* bufB = (unsigned short*)(ws + (80ull << 20));
    unsigned short* hbuf = (unsigned short*)(ws + (144ull << 20));

    const int countB = (E + 255) / 256;                 // 1954
    const int nxb = NB * 4;                             // 1564 castx blocks (32 rows each)
    const int gemmB = 8 * 4 * ((NB + 7) / 8);           // 1568 (128-tile grid, gemm1)
    const int gemm2B = 8 * 2 * ((MB2 + 7) / 8);         // 400 (256-tile grid, gemm2)

    hipMemsetAsync(cnt, 0, N * sizeof(int), stream);
    // [edge count | cast x (block-transpose)]
    fused_count_castx<<<countB + nxb, 256, 0, stream>>>(dst, cnt, E, countB,
                                                        x, bufA, N, nxb);
    // [block sums + norm | cast W1/W2/Wc]
    fused_bsum_castw<<<NSB + 288, 256, 0, stream>>>(cnt, normv, bsums, N, NSB,
                                                    W1, W2, Wc, W1t, W2t, Wct, NC);
    bscan_kernel<<<1, 256, 0, stream>>>(bsums, boffs, rowptr + N, NSB);
    scan_final_kernel<<<NSB, 256, 0, stream>>>(cnt, boffs, rowptr, cursor, N);
    // [CSR fill | gemm layer-1]
    fused_fill_gemm1<<<countB + gemmB, 256, 0, stream>>>(src, dst, normv, cursor, epair,
                                                         E, countB,
                                                         bufA, W1t, hbuf, N, NB);
    const int aggB = (N + 15) / 16;
    aggregate_kernel<<<aggB, 1024, 0, stream>>>(hbuf, rowptr, epair, normv, b1, bufB, N);
    gemm256_swz<<<gemm2B, 512, 0, stream>>>(bufB, W2t, hbuf, N, MB2);
    aggregate_kernel<<<aggB, 1024, 0, stream>>>(hbuf, rowptr, epair, normv, b2, bufA, N);
    gemm_plain<1><<<dim3(NB, 1), 256, 0, stream>>>(bufA, Wct, bc, d_out, N, NC);
}